// Round 8
// baseline (116.005 us; speedup 1.0000x reference)
//
#include <hip/hip_runtime.h>

// Problem constants (from reference setup_inputs)
#define BB 8
#define QQ 30
#define DD 1500
#define EE 768
#define KK 11
#define WW 736      // (1500-30)/2 + 1
#define WIN 30
#define STR 2

#define ESPL 16     // E split count (grid)
#define ECH 48      // e per split (12 float4, 24 e2-pairs)
#define NF4 (ECH / 4)
#define NE2 (ECH / 2)
#define DT 256      // d-tile per block
#define NDSUP 6     // ceil(1500/256)
#define RSTR 52     // LDS row stride in floats: 13 float4-slots, 16B-aligned rows
#define QT_STRIDE (EE / 2 * 2 * QQ)   // per-batch qnT stride = 384*60 = 23040

// ---------------------------------------------------------------------------
// Kernel 1: normalize q rows and write TRANSPOSED qnT[b][e2][q][2]
// (contiguous 60-dword blocks per e2 -> scalar-loadable in skl_cos)
// ---------------------------------------------------------------------------
__global__ __launch_bounds__(256) void skl_normq(
    const float* __restrict__ qe, float* __restrict__ qnT)
{
    int wid = threadIdx.x >> 6, lane = threadIdx.x & 63;
    int row = blockIdx.x * 4 + wid;
    if (row >= BB * QQ) return;
    int b = row / QQ, q = row - b * QQ;
    const float4* p = (const float4*)(qe + (size_t)row * EE);
    float4 v[3];
    float ss = 0.f;
    #pragma unroll
    for (int k = 0; k < 3; k++) {
        v[k] = p[lane + 64 * k];
        ss += v[k].x * v[k].x + v[k].y * v[k].y + v[k].z * v[k].z + v[k].w * v[k].w;
    }
    #pragma unroll
    for (int off = 32; off >= 1; off >>= 1) ss += __shfl_xor(ss, off);
    float inv = 1.f / fmaxf(sqrtf(ss), 1e-13f);
    float* base = qnT + (size_t)b * QT_STRIDE + 2 * q;
    #pragma unroll
    for (int k = 0; k < 3; k++) {
        int e2 = 2 * (lane + 64 * k);        // e-pair index of (x,y)
        *(float2*)&base[(size_t)e2 * (2 * QQ)] = make_float2(v[k].x * inv, v[k].y * inv);
        *(float2*)&base[(size_t)(e2 + 1) * (2 * QQ)] = make_float2(v[k].z * inv, v[k].w * inv);
    }
}

// ---------------------------------------------------------------------------
// Kernel 2 (v5): cos partials. d staged in LDS (coalesced HBM, read once
// per-thread into 48 regs, conflict-free b128); q via block-UNIFORM loads
// from qnT (scalar pipe, s_load) -> inner loop is pure v_fmac, zero LDS.
// Thread: 1 d-row x 30 q. grid = (6 d-sup, 16 e-chunks, 8 b) = 768 = 3/CU.
// ---------------------------------------------------------------------------
__global__ __launch_bounds__(256) void skl_cos(
    const float* __restrict__ de,     // [8][1500][768]
    const float* __restrict__ qnT,    // [8][384][30][2]
    float* __restrict__ cpart,        // [16][240][1500]
    float* __restrict__ dssq)         // [16][8][1500]
{
    __shared__ float ds[DT * RSTR];   // 53.2 KB -> 3 blocks/CU
    int tid = threadIdx.x;
    int dsup = blockIdx.x;   // 0..5
    int ec   = blockIdx.y;   // 0..15
    int b    = blockIdx.z;   // 0..7
    int dbase = dsup * DT;
    int e0 = ec * ECH;

    // stage d tile: 256 rows x 12 float4; consecutive threads cover
    // consecutive 16B of a row (coalesced global 192B segments)
    #pragma unroll
    for (int k = 0; k < 12; k++) {
        int f = tid + k * 256;
        int row = f / NF4, col4 = f - row * NF4;
        int drow = min(dbase + row, DD - 1);
        float4 v = *(const float4*)(de + ((size_t)b * DD + drow) * EE + e0 + col4 * 4);
        *(float4*)&ds[row * RSTR + col4 * 4] = v;
    }
    __syncthreads();

    // own d-row -> registers (12 conflict-free ds_read_b128 total)
    float dreg[ECH];
    #pragma unroll
    for (int k = 0; k < NF4; k++) {
        float4 v = *(const float4*)&ds[tid * RSTR + k * 4];
        dreg[4 * k + 0] = v.x; dreg[4 * k + 1] = v.y;
        dreg[4 * k + 2] = v.z; dreg[4 * k + 3] = v.w;
    }

    float ssq = 0.f;
    #pragma unroll
    for (int e = 0; e < ECH; e++) ssq += dreg[e] * dreg[e];

    float acc[QQ];
    #pragma unroll
    for (int q = 0; q < QQ; q++) acc[q] = 0.f;

    // q operand: block-uniform address -> scalar loads; FMA v*s
    const float* qp0 = qnT + (size_t)b * QT_STRIDE + (size_t)(e0 >> 1) * (2 * QQ);
    #pragma unroll
    for (int e2 = 0; e2 < NE2; e2++) {
        const float* qp = qp0 + e2 * (2 * QQ);
        float d0 = dreg[2 * e2], d1 = dreg[2 * e2 + 1];
        #pragma unroll
        for (int q = 0; q < QQ; q++) {
            acc[q] += qp[2 * q] * d0 + qp[2 * q + 1] * d1;
        }
    }

    int d = dbase + tid;
    if (d < DD) {
        #pragma unroll
        for (int q = 0; q < QQ; q++)
            cpart[((size_t)ec * BB * QQ + b * QQ + q) * DD + d] = acc[q];
        dssq[((size_t)ec * BB + b) * DD + d] = ssq;
    }
}

// ---------------------------------------------------------------------------
// Kernel 3: sum cos partials, invd inline, RBF (f32 __expf) -> window sums
// (f32, float2 LDS reads) -> saturation (f32 fast pow) -> dense_w.
// Block per (b,q,chunk of 256 windows).
// ---------------------------------------------------------------------------
#define DCH 544    // max d-extent a chunk needs (2*255+29+1 = 540, padded)

__global__ __launch_bounds__(256) void skl_windows(
    const float* __restrict__ cpart,   // [16][240][1500]
    const float* __restrict__ dssq,    // [16][8][1500]
    const float* __restrict__ dmask,   // [8][1500]
    const float* __restrict__ qmask,   // [8][30]
    const float* __restrict__ qidfs,   // [240]
    const float* __restrict__ mu,      // [11]
    const float* __restrict__ sigma,   // [11]
    const float* __restrict__ w1, const float* __restrict__ b1,
    const float* __restrict__ w2, const float* __restrict__ b2,
    const float* __restrict__ w3, const float* __restrict__ b3,
    const float* __restrict__ dw,      // [11]
    float* __restrict__ pscore)        // [240][736]
{
    __shared__ float vf[KK][DCH];      // 23.9 KB
    __shared__ float fl[DCH];          // 2.2 KB

    int bid = blockIdx.x;     // 0..719
    int c  = bid % 3;
    int bq = bid / 3;         // 0..239
    int b  = bq / QQ;
    int tid = threadIdx.x;

    int dbase = 512 * c;
    int dcount = min(540, DD - dbase);
    int w = c * 256 + tid;
    bool active = (w < WW);

    float muL[KK], i2s[KK], dwL[KK];
    #pragma unroll
    for (int k = 0; k < KK; k++) {
        muL[k] = mu[k];
        float s = sigma[k];
        i2s[k] = 1.f / (2.f * s * s);
        dwL[k] = dw[k];
    }
    const float* dm = dmask + (size_t)b * DD + dbase;

    // phase 1: sum e-partials, invd, mask, 11 RBF values per d
    for (int i = tid; i < dcount; i += 256) {
        int dg = dbase + i;
        float s = 0.f, sq = 0.f;
        #pragma unroll
        for (int p = 0; p < ESPL; p++) {
            s  += cpart[((size_t)p * BB * QQ + bq) * DD + dg];
            sq += dssq[((size_t)p * BB + b) * DD + dg];
        }
        float invd = 1.f / fmaxf(sqrtf(sq), 1e-13f);
        float cc = s * invd;
        float m = dm[i];
        float ssum = 0.f;
        #pragma unroll
        for (int k = 0; k < KK; k++) {
            float diff = cc - muL[k];
            float val = __expf(-diff * diff * i2s[k]) * m;
            ssum += val;
            vf[k][i] = val;
        }
        fl[i] = (ssum != 0.f) ? 1.f : 0.f;
    }
    __syncthreads();

    // phase 2: per-window sums + saturation + dense_w
    if (active) {
        int dl = 2 * tid;     // window covers d-pairs tid..tid+14 (8B-aligned)
        float pk[KK];
        #pragma unroll
        for (int k = 0; k < KK; k++) pk[k] = 0.f;
        float lenf = 0.f;
        #pragma unroll
        for (int j2 = 0; j2 < WIN / 2; j2++) {
            float2 f2 = *(const float2*)&fl[dl + 2 * j2];
            lenf += f2.x + f2.y;
            #pragma unroll
            for (int k = 0; k < KK; k++) {
                float2 v2 = *(const float2*)&vf[k][dl + 2 * j2];
                pk[k] += v2.x + v2.y;
            }
        }
        float idf = fmaxf(qidfs[bq], 0.f);
        float sat1 = idf * w1[0] + lenf * w1[1] + b1[0];
        float sat2 = 1.f / (idf * w2[0] + lenf * w2[1] + b2[0]);
        float sat3 = idf * w3[0] + lenf * w3[1] + b3[0];
        float mult = qmask[bq] * (lenf > 0.f ? 1.f : 0.f);

        float acc = 0.f;
        #pragma unroll
        for (int k = 0; k < KK; k++) {
            float x = fmaxf(pk[k], 1e-10f);
            float p = exp2f(sat2 * __log2f(x));
            acc += (sat1 * p - sat3) * dwL[k];
        }
        pscore[(size_t)bq * WW + w] = acc * mult;
    }
}

// ---------------------------------------------------------------------------
// Kernel 4: per batch: sum over q (256 threads), then single-wave top-3
// argmax + pooling + gather.
// ---------------------------------------------------------------------------
__global__ __launch_bounds__(256) void skl_topk(
    const float* __restrict__ pscore,  // [240][736]
    const float* __restrict__ chunk,   // [15]
    float* __restrict__ out)           // [8]
{
    __shared__ float s0[WW];
    int b = blockIdx.x;
    int tid = threadIdx.x;

    for (int w = tid; w < WW; w += 256) {
        float s = 0.f;
        for (int q = 0; q < QQ; q++) s += pscore[(size_t)(b * QQ + q) * WW + w];
        s0[w] = (s == 0.f) ? -9900.f : s;
    }
    __syncthreads();

    if (tid < 64) {
        int lane = tid;
        float m[12];
        #pragma unroll
        for (int r = 0; r < 12; r++) {
            int w = lane + 64 * r;
            m[r] = (w < WW) ? s0[w] : -3.3e38f;
        }

        int best[3];
        for (int c = 0; c < 3; c++) {
            float bv = -3.3e38f;
            int bi = 1 << 30;
            #pragma unroll
            for (int r = 0; r < 12; r++) {
                int w = lane + 64 * r;
                if (w < WW && m[r] > bv) { bv = m[r]; bi = w; }
            }
            #pragma unroll
            for (int off = 32; off >= 1; off >>= 1) {
                float ov = __shfl_down(bv, off);
                int oi = __shfl_down(bi, off);
                if (ov > bv || (ov == bv && oi < bi)) { bv = ov; bi = oi; }
            }
            bi = __shfl(bi, 0);
            best[c] = bi;
            float pen = -10001.f - (float)c;
            #pragma unroll
            for (int r = 0; r < 12; r++) {
                int w = lane + 64 * r;
                int dd = w - bi; if (dd < 0) dd = -dd;
                if (w < WW && dd < 15) m[r] = pen;
            }
        }

        float contrib = 0.f;
        if (lane < 15) {
            int c = lane % 3;
            int g = lane / 3;
            const int offs[5] = {0, -1, 1, -2, 2};
            int nb = best[c] + offs[g];
            nb = min(max(nb, 0), WW - 1);
            float v = s0[nb];
            if (v <= -9900.f) v = 0.f;
            contrib = v * chunk[lane];
        }
        #pragma unroll
        for (int off = 32; off >= 1; off >>= 1) contrib += __shfl_down(contrib, off);
        if (lane == 0) out[b] = contrib;
    }
}

// ---------------------------------------------------------------------------
extern "C" void kernel_launch(void* const* d_in, const int* in_sizes, int n_in,
                              void* d_out, int out_size, void* d_ws, size_t ws_size,
                              hipStream_t stream) {
    const float* qe    = (const float*)d_in[0];   // (8,30,768)
    const float* de    = (const float*)d_in[1];   // (8,1500,768)
    const float* qmask = (const float*)d_in[2];   // (8,30)
    const float* dmask = (const float*)d_in[3];   // (8,1500)
    const float* qidfs = (const float*)d_in[4];   // (8,30,1)
    // d_in[5] = document_idfs (unused by reference)
    const float* mu    = (const float*)d_in[6];   // (11,)
    const float* sigma = (const float*)d_in[7];   // (11,)
    const float* w1    = (const float*)d_in[8];
    const float* b1    = (const float*)d_in[9];
    const float* w2    = (const float*)d_in[10];
    const float* b2    = (const float*)d_in[11];
    const float* w3    = (const float*)d_in[12];
    const float* b3    = (const float*)d_in[13];
    const float* dw    = (const float*)d_in[14];  // (1,11)
    const float* chunk = (const float*)d_in[15];  // (1,15)
    float* out = (float*)d_out;

    float* ws = (float*)d_ws;
    float* cpart  = ws;                    // 16*240*1500 = 5,760,000
    float* dssq   = ws + 5760000;          // 16*8*1500   =   192,000
    float* qnT    = ws + 5952000;          // 8*384*60    =   184,320
    float* pscore = ws + 6136320;          // 240*736     =   176,640  (~25.3MB)

    skl_normq<<<60, 256, 0, stream>>>(qe, qnT);
    skl_cos<<<dim3(NDSUP, ESPL, BB), 256, 0, stream>>>(de, qnT, cpart, dssq);
    skl_windows<<<BB * QQ * 3, 256, 0, stream>>>(cpart, dssq, dmask, qmask, qidfs,
                                                 mu, sigma, w1, b1, w2, b2, w3, b3,
                                                 dw, pscore);
    skl_topk<<<BB, 256, 0, stream>>>(pscore, chunk, out);
}

// Round 9
// 42.851 us; speedup vs baseline: 2.7072x; 2.7072x over previous
//
#include <hip/hip_runtime.h>

// Problem constants (from reference setup_inputs)
#define BB 8
#define QQ 30
#define DD 1500
#define EE 768
#define KK 11
#define WW 736      // (1500-30)/2 + 1
#define WIN 30
#define STR 2

#define KSPL 8      // K-split (8 x 96 e); also windows partial count
#define ESPL KSPL
#define NCH 12      // n-chunks of 128 d (8 n-tiles of 16)

typedef __attribute__((ext_vector_type(8))) __bf16 bf16x8;
typedef __attribute__((ext_vector_type(4))) float f32x4;
typedef __attribute__((ext_vector_type(4))) unsigned int uint4v;

__device__ inline unsigned int f2bf(float x) {   // f32 -> bf16 bits, RNE
    unsigned int u = __float_as_uint(x);
    return (u + 0x7fffu + ((u >> 16) & 1u)) >> 16;
}

// ---------------------------------------------------------------------------
// Kernel 1: normalize q rows, split to bf16 hi/lo, pad to 32 rows (zeros)
// qh/ql layout: [b][32][768] ushort
// ---------------------------------------------------------------------------
__global__ __launch_bounds__(256) void skl_normq(
    const float* __restrict__ qe, ushort* __restrict__ qh, ushort* __restrict__ ql)
{
    int wid = threadIdx.x >> 6, lane = threadIdx.x & 63;
    int r = blockIdx.x * 4 + wid;        // 0..255 = b*32+q
    if (r >= BB * 32) return;
    int b = r >> 5, q = r & 31;
    ushort* ph = qh + (size_t)r * EE;
    ushort* pl = ql + (size_t)r * EE;
    if (q >= QQ) {
        #pragma unroll
        for (int k = 0; k < 3; k++) {
            int e = (lane + 64 * k) * 4;
            *(ushort4*)&ph[e] = make_ushort4(0, 0, 0, 0);
            *(ushort4*)&pl[e] = make_ushort4(0, 0, 0, 0);
        }
        return;
    }
    const float4* p = (const float4*)(qe + (size_t)(b * QQ + q) * EE);
    float4 v[3];
    float ss = 0.f;
    #pragma unroll
    for (int k = 0; k < 3; k++) {
        v[k] = p[lane + 64 * k];
        ss += v[k].x * v[k].x + v[k].y * v[k].y + v[k].z * v[k].z + v[k].w * v[k].w;
    }
    #pragma unroll
    for (int off = 32; off >= 1; off >>= 1) ss += __shfl_xor(ss, off);
    float inv = 1.f / fmaxf(sqrtf(ss), 1e-13f);
    #pragma unroll
    for (int k = 0; k < 3; k++) {
        float f[4] = {v[k].x * inv, v[k].y * inv, v[k].z * inv, v[k].w * inv};
        ushort hs[4], ls[4];
        #pragma unroll
        for (int j = 0; j < 4; j++) {
            unsigned h = f2bf(f[j]);
            float hf = __uint_as_float(h << 16);
            unsigned l = f2bf(f[j] - hf);
            hs[j] = (ushort)h; ls[j] = (ushort)l;
        }
        int e = (lane + 64 * k) * 4;
        *(ushort4*)&ph[e] = make_ushort4(hs[0], hs[1], hs[2], hs[3]);
        *(ushort4*)&pl[e] = make_ushort4(ls[0], ls[1], ls[2], ls[3]);
    }
}

// ---------------------------------------------------------------------------
// helper: 8 f32 -> split bf16x8 (hi, lo) + ssq accumulate
// ---------------------------------------------------------------------------
__device__ inline void split8(const float4 va, const float4 vb,
                              bf16x8& bh, bf16x8& bl, float& ssq)
{
    float f[8] = {va.x, va.y, va.z, va.w, vb.x, vb.y, vb.z, vb.w};
    unsigned hu[8], lu[8];
    #pragma unroll
    for (int j = 0; j < 8; j++) {
        float x = f[j];
        ssq += x * x;
        unsigned h = f2bf(x);
        float hf = __uint_as_float(h << 16);
        unsigned l = f2bf(x - hf);
        hu[j] = h; lu[j] = l;
    }
    uint4v uh = {hu[0] | (hu[1] << 16), hu[2] | (hu[3] << 16),
                 hu[4] | (hu[5] << 16), hu[6] | (hu[7] << 16)};
    uint4v ul = {lu[0] | (lu[1] << 16), lu[2] | (lu[3] << 16),
                 lu[4] | (lu[5] << 16), lu[6] | (lu[7] << 16)};
    bh = __builtin_bit_cast(bf16x8, uh);
    bl = __builtin_bit_cast(bf16x8, ul);
}

#define MFMA(a, b, c) __builtin_amdgcn_mfma_f32_16x16x32_bf16(a, b, c, 0, 0, 0)

// ---------------------------------------------------------------------------
// Kernel 2 (v6): split-bf16 MFMA GEMM. C[q][d] = qn . de  (per batch)
// Wave owns 2 n-tiles x both m-tiles; 3 K-steps of 32 per block (K-split 8).
// B built in-registers from f32 de (each element converted exactly once
// across the grid); ssq from same registers. No LDS, no barriers.
// grid = (12 n-chunks, 8 k-splits, 8 batches) = 768 blocks.
// ---------------------------------------------------------------------------
__global__ __launch_bounds__(256) void skl_gemm(
    const float* __restrict__ de,      // [8][1500][768] f32
    const ushort* __restrict__ qh,     // [8][32][768] bf16 bits
    const ushort* __restrict__ ql,
    float* __restrict__ cpart,         // [8][240][1500]
    float* __restrict__ dssq)          // [8][8][1500]
{
    int tid = threadIdx.x;
    int wave = tid >> 6, lane = tid & 63;
    int ln = lane & 15, g = lane >> 4;
    int nch = blockIdx.x, ks = blockIdx.y, b = blockIdx.z;
    int nt0 = nch * 8 + wave * 2;          // this wave's n-tiles: nt0, nt0+1
    int d0 = nt0 * 16 + ln;
    int d1 = d0 + 16;
    int d0c = min(d0, DD - 1), d1c = min(d1, DD - 1);
    const float* drow0 = de + ((size_t)b * DD + d0c) * EE;
    const float* drow1 = de + ((size_t)b * DD + d1c) * EE;
    const ushort* qhb = qh + (size_t)b * 32 * EE;
    const ushort* qlb = ql + (size_t)b * 32 * EE;

    f32x4 acc00 = {0.f, 0.f, 0.f, 0.f};   // [m-tile][n-tile]
    f32x4 acc01 = {0.f, 0.f, 0.f, 0.f};
    f32x4 acc10 = {0.f, 0.f, 0.f, 0.f};
    f32x4 acc11 = {0.f, 0.f, 0.f, 0.f};
    float ssq0 = 0.f, ssq1 = 0.f;

    #pragma unroll
    for (int kst = 0; kst < 3; kst++) {
        int e0 = ks * 96 + kst * 32 + 8 * g;
        bf16x8 a0h = *(const bf16x8*)&qhb[(size_t)ln * EE + e0];
        bf16x8 a0l = *(const bf16x8*)&qlb[(size_t)ln * EE + e0];
        bf16x8 a1h = *(const bf16x8*)&qhb[(size_t)(16 + ln) * EE + e0];
        bf16x8 a1l = *(const bf16x8*)&qlb[(size_t)(16 + ln) * EE + e0];

        float4 v0a = *(const float4*)&drow0[e0];
        float4 v0b = *(const float4*)&drow0[e0 + 4];
        float4 v1a = *(const float4*)&drow1[e0];
        float4 v1b = *(const float4*)&drow1[e0 + 4];
        bf16x8 b0h, b0l, b1h, b1l;
        split8(v0a, v0b, b0h, b0l, ssq0);
        split8(v1a, v1b, b1h, b1l, ssq1);

        acc00 = MFMA(a0h, b0h, acc00);
        acc00 = MFMA(a0h, b0l, acc00);
        acc00 = MFMA(a0l, b0h, acc00);
        acc01 = MFMA(a0h, b1h, acc01);
        acc01 = MFMA(a0h, b1l, acc01);
        acc01 = MFMA(a0l, b1h, acc01);
        acc10 = MFMA(a1h, b0h, acc10);
        acc10 = MFMA(a1h, b0l, acc10);
        acc10 = MFMA(a1l, b0h, acc10);
        acc11 = MFMA(a1h, b1h, acc11);
        acc11 = MFMA(a1h, b1l, acc11);
        acc11 = MFMA(a1l, b1h, acc11);
    }

    // ssq row-sums: reduce over the 4 k-group lanes (same ln)
    ssq0 += __shfl_xor(ssq0, 16); ssq0 += __shfl_xor(ssq0, 32);
    ssq1 += __shfl_xor(ssq1, 16); ssq1 += __shfl_xor(ssq1, 32);
    if (lane < 16) {
        if (d0 < DD) dssq[((size_t)ks * BB + b) * DD + d0] = ssq0;
        if (d1 < DD) dssq[((size_t)ks * BB + b) * DD + d1] = ssq1;
    }

    // C store: D[m][n]: m = 4*g + j, n = ln (m89-verified layout)
    #pragma unroll
    for (int j = 0; j < 4; j++) {
        int q0 = 4 * g + j;          // m-tile 0 row (<16, always valid)
        int q1 = 16 + q0;            // m-tile 1 row (valid if <30)
        size_t base0 = ((size_t)ks * (BB * QQ) + b * QQ + q0) * DD;
        if (d0 < DD) cpart[base0 + d0] = acc00[j];
        if (d1 < DD) cpart[base0 + d1] = acc01[j];
        if (q1 < QQ) {
            size_t base1 = ((size_t)ks * (BB * QQ) + b * QQ + q1) * DD;
            if (d0 < DD) cpart[base1 + d0] = acc10[j];
            if (d1 < DD) cpart[base1 + d1] = acc11[j];
        }
    }
}

// ---------------------------------------------------------------------------
// Kernel 3: sum cos partials, invd inline, RBF (f32 __expf) -> window sums
// (f32, float2 LDS reads) -> saturation (f32 fast pow) -> dense_w.
// Block per (b,q,chunk of 256 windows).
// ---------------------------------------------------------------------------
#define DCH 544    // max d-extent a chunk needs (2*255+29+1 = 540, padded)

__global__ __launch_bounds__(256) void skl_windows(
    const float* __restrict__ cpart,   // [8][240][1500]
    const float* __restrict__ dssq,    // [8][8][1500]
    const float* __restrict__ dmask,   // [8][1500]
    const float* __restrict__ qmask,   // [8][30]
    const float* __restrict__ qidfs,   // [240]
    const float* __restrict__ mu,      // [11]
    const float* __restrict__ sigma,   // [11]
    const float* __restrict__ w1, const float* __restrict__ b1,
    const float* __restrict__ w2, const float* __restrict__ b2,
    const float* __restrict__ w3, const float* __restrict__ b3,
    const float* __restrict__ dw,      // [11]
    float* __restrict__ pscore)        // [240][736]
{
    __shared__ float vf[KK][DCH];      // 23.9 KB
    __shared__ float fl[DCH];          // 2.2 KB

    int bid = blockIdx.x;     // 0..719
    int c  = bid % 3;
    int bq = bid / 3;         // 0..239
    int b  = bq / QQ;
    int tid = threadIdx.x;

    int dbase = 512 * c;
    int dcount = min(540, DD - dbase);
    int w = c * 256 + tid;
    bool active = (w < WW);

    float muL[KK], i2s[KK], dwL[KK];
    #pragma unroll
    for (int k = 0; k < KK; k++) {
        muL[k] = mu[k];
        float s = sigma[k];
        i2s[k] = 1.f / (2.f * s * s);
        dwL[k] = dw[k];
    }
    const float* dm = dmask + (size_t)b * DD + dbase;

    // phase 1: sum e-partials, invd, mask, 11 RBF values per d
    for (int i = tid; i < dcount; i += 256) {
        int dg = dbase + i;
        float s = 0.f, sq = 0.f;
        #pragma unroll
        for (int p = 0; p < ESPL; p++) {
            s  += cpart[((size_t)p * BB * QQ + bq) * DD + dg];
            sq += dssq[((size_t)p * BB + b) * DD + dg];
        }
        float invd = 1.f / fmaxf(sqrtf(sq), 1e-13f);
        float cc = s * invd;
        float m = dm[i];
        float ssum = 0.f;
        #pragma unroll
        for (int k = 0; k < KK; k++) {
            float diff = cc - muL[k];
            float val = __expf(-diff * diff * i2s[k]) * m;
            ssum += val;
            vf[k][i] = val;
        }
        fl[i] = (ssum != 0.f) ? 1.f : 0.f;
    }
    __syncthreads();

    // phase 2: per-window sums + saturation + dense_w
    if (active) {
        int dl = 2 * tid;     // window covers d-pairs tid..tid+14 (8B-aligned)
        float pk[KK];
        #pragma unroll
        for (int k = 0; k < KK; k++) pk[k] = 0.f;
        float lenf = 0.f;
        #pragma unroll
        for (int j2 = 0; j2 < WIN / 2; j2++) {
            float2 f2 = *(const float2*)&fl[dl + 2 * j2];
            lenf += f2.x + f2.y;
            #pragma unroll
            for (int k = 0; k < KK; k++) {
                float2 v2 = *(const float2*)&vf[k][dl + 2 * j2];
                pk[k] += v2.x + v2.y;
            }
        }
        float idf = fmaxf(qidfs[bq], 0.f);
        float sat1 = idf * w1[0] + lenf * w1[1] + b1[0];
        float sat2 = 1.f / (idf * w2[0] + lenf * w2[1] + b2[0]);
        float sat3 = idf * w3[0] + lenf * w3[1] + b3[0];
        float mult = qmask[bq] * (lenf > 0.f ? 1.f : 0.f);

        float acc = 0.f;
        #pragma unroll
        for (int k = 0; k < KK; k++) {
            float x = fmaxf(pk[k], 1e-10f);
            float p = exp2f(sat2 * __log2f(x));
            acc += (sat1 * p - sat3) * dwL[k];
        }
        pscore[(size_t)bq * WW + w] = acc * mult;
    }
}

// ---------------------------------------------------------------------------
// Kernel 4: per batch: sum over q (256 threads), then single-wave top-3
// argmax + pooling + gather.
// ---------------------------------------------------------------------------
__global__ __launch_bounds__(256) void skl_topk(
    const float* __restrict__ pscore,  // [240][736]
    const float* __restrict__ chunk,   // [15]
    float* __restrict__ out)           // [8]
{
    __shared__ float s0[WW];
    int b = blockIdx.x;
    int tid = threadIdx.x;

    for (int w = tid; w < WW; w += 256) {
        float s = 0.f;
        for (int q = 0; q < QQ; q++) s += pscore[(size_t)(b * QQ + q) * WW + w];
        s0[w] = (s == 0.f) ? -9900.f : s;
    }
    __syncthreads();

    if (tid < 64) {
        int lane = tid;
        float m[12];
        #pragma unroll
        for (int r = 0; r < 12; r++) {
            int w = lane + 64 * r;
            m[r] = (w < WW) ? s0[w] : -3.3e38f;
        }

        int best[3];
        for (int c = 0; c < 3; c++) {
            float bv = -3.3e38f;
            int bi = 1 << 30;
            #pragma unroll
            for (int r = 0; r < 12; r++) {
                int w = lane + 64 * r;
                if (w < WW && m[r] > bv) { bv = m[r]; bi = w; }
            }
            #pragma unroll
            for (int off = 32; off >= 1; off >>= 1) {
                float ov = __shfl_down(bv, off);
                int oi = __shfl_down(bi, off);
                if (ov > bv || (ov == bv && oi < bi)) { bv = ov; bi = oi; }
            }
            bi = __shfl(bi, 0);
            best[c] = bi;
            float pen = -10001.f - (float)c;
            #pragma unroll
            for (int r = 0; r < 12; r++) {
                int w = lane + 64 * r;
                int dd = w - bi; if (dd < 0) dd = -dd;
                if (w < WW && dd < 15) m[r] = pen;
            }
        }

        float contrib = 0.f;
        if (lane < 15) {
            int c = lane % 3;
            int g = lane / 3;
            const int offs[5] = {0, -1, 1, -2, 2};
            int nb = best[c] + offs[g];
            nb = min(max(nb, 0), WW - 1);
            float v = s0[nb];
            if (v <= -9900.f) v = 0.f;
            contrib = v * chunk[lane];
        }
        #pragma unroll
        for (int off = 32; off >= 1; off >>= 1) contrib += __shfl_down(contrib, off);
        if (lane == 0) out[b] = contrib;
    }
}

// ---------------------------------------------------------------------------
extern "C" void kernel_launch(void* const* d_in, const int* in_sizes, int n_in,
                              void* d_out, int out_size, void* d_ws, size_t ws_size,
                              hipStream_t stream) {
    const float* qe    = (const float*)d_in[0];   // (8,30,768)
    const float* de    = (const float*)d_in[1];   // (8,1500,768)
    const float* qmask = (const float*)d_in[2];   // (8,30)
    const float* dmask = (const float*)d_in[3];   // (8,1500)
    const float* qidfs = (const float*)d_in[4];   // (8,30,1)
    // d_in[5] = document_idfs (unused by reference)
    const float* mu    = (const float*)d_in[6];   // (11,)
    const float* sigma = (const float*)d_in[7];   // (11,)
    const float* w1    = (const float*)d_in[8];
    const float* b1    = (const float*)d_in[9];
    const float* w2    = (const float*)d_in[10];
    const float* b2    = (const float*)d_in[11];
    const float* w3    = (const float*)d_in[12];
    const float* b3    = (const float*)d_in[13];
    const float* dw    = (const float*)d_in[14];  // (1,11)
    const float* chunk = (const float*)d_in[15];  // (1,15)
    float* out = (float*)d_out;

    float* ws = (float*)d_ws;
    float* cpart  = ws;                      // 8*240*1500 = 2,880,000 f32
    float* dssq   = ws + 2880000;            // 8*8*1500   =    96,000 f32
    float* pscore = ws + 2976000;            // 240*736    =   176,640 f32
    ushort* qh    = (ushort*)(ws + 3152640); // 8*32*768 ushort = 98,304 f32-slots
    ushort* ql    = (ushort*)(ws + 3250944); // same          (~13.4MB total)

    skl_normq<<<64, 256, 0, stream>>>(qe, qh, ql);
    skl_gemm<<<dim3(NCH, KSPL, BB), 256, 0, stream>>>(de, qh, ql, cpart, dssq);
    skl_windows<<<BB * QQ * 3, 256, 0, stream>>>(cpart, dssq, dmask, qmask, qidfs,
                                                 mu, sigma, w1, b1, w2, b2, w3, b3,
                                                 dw, pscore);
    skl_topk<<<BB, 256, 0, stream>>>(pscore, chunk, out);
}